// Round 2
// baseline (526.121 us; speedup 1.0000x reference)
//
#include <hip/hip_runtime.h>

typedef _Float16 f16;
typedef _Float16 f16x8 __attribute__((ext_vector_type(8)));
typedef float f32x4 __attribute__((ext_vector_type(4)));

#define IN_DIM  8192
#define OUT_DIM 8192
#define BATCH   256
#define BK      32
#define BN      128
#define NSPLIT  8
#define KSPL    (IN_DIM / NSPLIT)   /* 1024 per split */
#define NSTEP   (KSPL / BK)         /* 32 K-steps */

__device__ __forceinline__ float softplus_f(float r) {
    // rho ~ N(-3, 0.1): exp can't overflow; fast hw exp/log is ~1e-5 rel,
    // far below the f16 rounding we apply afterwards.
    return __logf(1.0f + __expf(r));
}

// Issue next K-step's global loads into a named register set (10 x f32x4).
#define ISSUE(S, A0a,A0b,A1a,A1b,M0,M1,R0,R1,E0,E1) do {                     \
    const int o_ = (S) * BK;                                                 \
    A0a = *(const f32x4*)(xp0 + o_);   A0b = *(const f32x4*)(xp0 + o_ + 4);  \
    A1a = *(const f32x4*)(xp1 + o_);   A1b = *(const f32x4*)(xp1 + o_ + 4);  \
    M0  = *(const f32x4*)(mup + o_);   M1  = *(const f32x4*)(mup + o_ + 4);  \
    R0  = *(const f32x4*)(rhp + o_);   R1  = *(const f32x4*)(rhp + o_ + 4);  \
    E0  = *(const f32x4*)(epp + o_);   E1  = *(const f32x4*)(epp + o_ + 4);  \
} while (0)

// Convert + softplus-combine and ds_write_b128 into LDS buffer BUF.
#define COMMIT(BUF, A0a,A0b,A1a,A1b,M0,M1,R0,R1,E0,E1) do {                  \
    f16x8 av0_, av1_, wv_;                                                   \
    _Pragma("unroll")                                                        \
    for (int q_ = 0; q_ < 4; ++q_) {                                         \
        av0_[q_]   = (f16)A0a[q_];  av0_[4+q_] = (f16)A0b[q_];               \
        av1_[q_]   = (f16)A1a[q_];  av1_[4+q_] = (f16)A1b[q_];               \
        wv_[q_]   = (f16)(M0[q_] + softplus_f(R0[q_]) * E0[q_]);             \
        wv_[4+q_] = (f16)(M1[q_] + softplus_f(R1[q_]) * E1[q_]);             \
    }                                                                        \
    *(f16x8*)&sm[BUF][a_st0] = av0_;                                         \
    *(f16x8*)&sm[BUF][a_st1] = av1_;                                         \
    *(f16x8*)&sm[BUF][b_st]  = wv_;                                          \
} while (0)

// One K-step of MFMA: 4x4 fragments of 16x16x32 f16 per wave (64x64 tile).
// Swizzle (slot ^ ((row>>1)&3)) spreads the 16 rows of one fragment read
// across all 8 16B bank-groups -> 2-way (free, m136).
#define MSTEP(BUF) do {                                                      \
    f16x8 af_[4], bf_[4];                                                    \
    const int sl_ = lane >> 4;                                               \
    _Pragma("unroll")                                                        \
    for (int i_ = 0; i_ < 4; ++i_) {                                         \
        const int ar_ = wm * 64 + i_ * 16 + (lane & 15);                     \
        af_[i_] = *(const f16x8*)&sm[BUF][ar_ * BK + ((sl_ ^ ((ar_ >> 1) & 3)) << 3)]; \
        const int br_ = wn * 64 + i_ * 16 + (lane & 15);                     \
        bf_[i_] = *(const f16x8*)&sm[BUF][BATCH * BK + br_ * BK + ((sl_ ^ ((br_ >> 1) & 3)) << 3)]; \
    }                                                                        \
    _Pragma("unroll")                                                        \
    for (int i_ = 0; i_ < 4; ++i_)                                           \
        _Pragma("unroll")                                                    \
        for (int j_ = 0; j_ < 4; ++j_)                                       \
            acc[i_][j_] = __builtin_amdgcn_mfma_f32_16x16x32_f16(            \
                af_[i_], bf_[j_], acc[i_][j_], 0, 0, 0);                     \
} while (0)

// Barrier that drains only LDS ops; global loads stay in flight across it.
#define BARRIER() do {                                                       \
    asm volatile("s_waitcnt lgkmcnt(0)" ::: "memory");                       \
    __builtin_amdgcn_s_barrier();                                            \
} while (0)

__global__ __launch_bounds__(512, 4)
void vl_main(const float* __restrict__ x,
             const float* __restrict__ muw,
             const float* __restrict__ rhow,
             const float* __restrict__ epsw,
             const float* __restrict__ mub,
             const float* __restrict__ rhob,
             const float* __restrict__ epsb,
             float* __restrict__ out)
{
    // A tile [256][32] f16 + B tile [128][32] f16, double-buffered = 48 KiB
    // -> 2 blocks/CU (96 KiB LDS, 16 waves/CU): one block's loads cover the
    // other block's barrier drains.
    __shared__ __align__(16) f16 sm[2][BATCH * BK + BN * BK];

    const int t    = threadIdx.x;
    const int lane = t & 63;
    const int wid  = t >> 6;     // 0..7
    const int wm   = wid >> 1;   // 0..3 : m0 = wm*64
    const int wn   = wid & 1;    // 0..1 : n0 = wn*64

    // XCD-aware mapping: XCD (= bx%8) owns one k-split; its 1 MiB x-chunk
    // stays L2-resident across the XCD's 64 blocks.
    const int bx = blockIdx.x;
    const int sk = bx & 7;       // 0..7 k-split == XCD
    const int nb = bx >> 3;      // 0..63 n-block
    const int k_base = sk * KSPL;
    const int n_base = nb * BN;

    // staging assignment: thread -> (row = t>>2, 16B slot = t&3)
    const int slot = t & 3;
    const int row  = t >> 2;     // 0..127

    const float* xp0 = x + (size_t)row * IN_DIM + k_base + slot * 8;
    const float* xp1 = xp0 + (size_t)128 * IN_DIM;
    const size_t woff = (size_t)(n_base + row) * IN_DIM + k_base + slot * 8;
    const float* mup = muw  + woff;
    const float* rhp = rhow + woff;
    const float* epp = epsw + woff;

    // XOR-swizzled LDS half-indices; write side covers each row's full 64 B
    // with 4 lanes -> 2-way regardless of the permutation.
    const int a_sw  = (slot ^ ((row >> 1) & 3)) << 3;
    const int a_st0 = row * BK + a_sw;
    const int a_st1 = (row + 128) * BK + a_sw;   // (row+128)>>1 & 3 == (row>>1)&3
    const int b_st  = BATCH * BK + row * BK + a_sw;

    f32x4 acc[4][4];
#pragma unroll
    for (int i = 0; i < 4; ++i)
#pragma unroll
        for (int j = 0; j < 4; ++j)
            acc[i][j] = (f32x4){0.f, 0.f, 0.f, 0.f};

    // Two named register sets (static indexing -> no scratch, rule #20).
    f32x4 A0a0,A0b0,A1a0,A1b0,M00,M10,R00,R10,E00,E10;  // set0
    f32x4 A0a1,A0b1,A1a1,A1b1,M01,M11,R01,R11,E01,E11;  // set1

    // Prologue: set0 <- k0, set1 <- k1, commit k0 into buf0.
    ISSUE(0, A0a0,A0b0,A1a0,A1b0,M00,M10,R00,R10,E00,E10);
    ISSUE(1, A0a1,A0b1,A1a1,A1b1,M01,M11,R01,R11,E01,E11);
    COMMIT(0, A0a0,A0b0,A1a0,A1b0,M00,M10,R00,R10,E00,E10);
    BARRIER();

    for (int s = 0; s < NSTEP; s += 2) {
        // even step: compute buf0 (k=s), commit set1 (k=s+1) -> buf1,
        // prefetch k=s+2 into set0.
        if (s + 2 < NSTEP) ISSUE(s + 2, A0a0,A0b0,A1a0,A1b0,M00,M10,R00,R10,E00,E10);
        MSTEP(0);
        COMMIT(1, A0a1,A0b1,A1a1,A1b1,M01,M11,R01,R11,E01,E11);
        BARRIER();
        // odd step: compute buf1 (k=s+1), commit set0 (k=s+2) -> buf0,
        // prefetch k=s+3 into set1.
        if (s + 3 < NSTEP) ISSUE(s + 3, A0a1,A0b1,A1a1,A1b1,M01,M11,R01,R11,E01,E11);
        MSTEP(1);
        if (s + 2 < NSTEP) COMMIT(0, A0a0,A0b0,A1a0,A1b0,M00,M10,R00,R10,E00,E10);
        BARRIER();
    }

    // Epilogue: bias (only k-split 0 adds it), then one f32 atomicAdd per
    // output element per split (d_out zeroed by hipMemsetAsync in launch).
    float bias[4] = {0.f, 0.f, 0.f, 0.f};
    if (sk == 0) {
#pragma unroll
        for (int j = 0; j < 4; ++j) {
            const int c = n_base + wn * 64 + j * 16 + (lane & 15);
            bias[j] = mub[c] + softplus_f(rhob[c]) * epsb[c];
        }
    }
#pragma unroll
    for (int i = 0; i < 4; ++i) {
        const int r = wm * 64 + i * 16 + ((lane >> 4) << 2);
#pragma unroll
        for (int j = 0; j < 4; ++j) {
            const int c = n_base + wn * 64 + j * 16 + (lane & 15);
            float* po = out + (size_t)r * OUT_DIM + c;
#pragma unroll
            for (int q = 0; q < 4; ++q)
                atomicAdd(po + (size_t)q * OUT_DIM, acc[i][j][q] + bias[j]);
        }
    }
}

extern "C" void kernel_launch(void* const* d_in, const int* in_sizes, int n_in,
                              void* d_out, int out_size, void* d_ws, size_t ws_size,
                              hipStream_t stream) {
    (void)in_sizes; (void)n_in; (void)d_ws; (void)ws_size;
    const float* x    = (const float*)d_in[0];
    const float* muw  = (const float*)d_in[1];
    const float* rhow = (const float*)d_in[2];
    const float* mub  = (const float*)d_in[3];
    const float* rhob = (const float*)d_in[4];
    const float* epsw = (const float*)d_in[5];
    const float* epsb = (const float*)d_in[6];
    float* out = (float*)d_out;

    hipMemsetAsync(out, 0, (size_t)out_size * sizeof(float), stream);
    vl_main<<<dim3(512), dim3(512), 0, stream>>>(x, muw, rhow, epsw,
                                                 mub, rhob, epsb, out);
}

// Round 3
// 280.031 us; speedup vs baseline: 1.8788x; 1.8788x over previous
//
#include <hip/hip_runtime.h>

typedef _Float16 f16;
typedef _Float16 f16x8 __attribute__((ext_vector_type(8)));
typedef float f32x4 __attribute__((ext_vector_type(4)));

#define IN_DIM  8192
#define OUT_DIM 8192
#define BATCH   256
#define BK      32
#define BN      128
#define NSPLIT  8
#define KSPL    (IN_DIM / NSPLIT)   /* 1024 per split */
#define NSTEP   (KSPL / BK)         /* 32 K-steps */

__device__ __forceinline__ float softplus_f(float r) {
    // rho ~ N(-3, 0.1): exp can't overflow; fast hw exp/log is ~1e-5 rel,
    // far below the f16 rounding we apply afterwards.
    return __logf(1.0f + __expf(r));
}

// Single prefetch register set (10 x f32x4 = 40 VGPRs) -- depth-1 pipeline.
// Two sets (80 VGPRs) + 64-reg accumulator blew the (512,4) cap in R2 and
// spilled to scratch (WRITE_SIZE 64 MiB -> 1 GB). One set fits.
#define ISSUE(S) do {                                                        \
    const int o_ = (S) * BK;                                                 \
    A0a = *(const f32x4*)(xp0 + o_);   A0b = *(const f32x4*)(xp0 + o_ + 4);  \
    A1a = *(const f32x4*)(xp1 + o_);   A1b = *(const f32x4*)(xp1 + o_ + 4);  \
    M0  = *(const f32x4*)(mup + o_);   M1  = *(const f32x4*)(mup + o_ + 4);  \
    R0  = *(const f32x4*)(rhp + o_);   R1  = *(const f32x4*)(rhp + o_ + 4);  \
    E0  = *(const f32x4*)(epp + o_);   E1  = *(const f32x4*)(epp + o_ + 4);  \
} while (0)

// Convert + softplus-combine and ds_write_b128 into LDS buffer BUF.
// (vmcnt wait for ISSUE's loads is inserted here by the compiler, i.e.
// after MSTEP -- load latency hides under the MFMAs.)
#define COMMIT(BUF) do {                                                     \
    f16x8 av0_, av1_, wv_;                                                   \
    _Pragma("unroll")                                                        \
    for (int q_ = 0; q_ < 4; ++q_) {                                         \
        av0_[q_]   = (f16)A0a[q_];  av0_[4+q_] = (f16)A0b[q_];               \
        av1_[q_]   = (f16)A1a[q_];  av1_[4+q_] = (f16)A1b[q_];               \
        wv_[q_]   = (f16)(M0[q_] + softplus_f(R0[q_]) * E0[q_]);             \
        wv_[4+q_] = (f16)(M1[q_] + softplus_f(R1[q_]) * E1[q_]);             \
    }                                                                        \
    *(f16x8*)&sm[BUF][a_st0] = av0_;                                         \
    *(f16x8*)&sm[BUF][a_st1] = av1_;                                         \
    *(f16x8*)&sm[BUF][b_st]  = wv_;                                          \
} while (0)

// One K-step of MFMA: 4x4 fragments of 16x16x32 f16 per wave (64x64 tile).
// Swizzle (slot ^ ((row>>1)&3)) spreads the 16 rows of one fragment read
// across all 8 16B bank-groups -> 2-way (free, m136). R2 measured
// SQ_LDS_BANK_CONFLICT = 0 with this pattern.
#define MSTEP(BUF) do {                                                      \
    f16x8 af_[4], bf_[4];                                                    \
    const int sl_ = lane >> 4;                                               \
    _Pragma("unroll")                                                        \
    for (int i_ = 0; i_ < 4; ++i_) {                                         \
        const int ar_ = wm * 64 + i_ * 16 + (lane & 15);                     \
        af_[i_] = *(const f16x8*)&sm[BUF][ar_ * BK + ((sl_ ^ ((ar_ >> 1) & 3)) << 3)]; \
        const int br_ = wn * 64 + i_ * 16 + (lane & 15);                     \
        bf_[i_] = *(const f16x8*)&sm[BUF][BATCH * BK + br_ * BK + ((sl_ ^ ((br_ >> 1) & 3)) << 3)]; \
    }                                                                        \
    _Pragma("unroll")                                                        \
    for (int i_ = 0; i_ < 4; ++i_)                                           \
        _Pragma("unroll")                                                    \
        for (int j_ = 0; j_ < 4; ++j_)                                       \
            acc[i_][j_] = __builtin_amdgcn_mfma_f32_16x16x32_f16(            \
                af_[i_], bf_[j_], acc[i_][j_], 0, 0, 0);                     \
} while (0)

// Barrier that drains only LDS ops; global loads stay in flight across it.
#define BARRIER() do {                                                       \
    asm volatile("s_waitcnt lgkmcnt(0)" ::: "memory");                       \
    __builtin_amdgcn_s_barrier();                                            \
} while (0)

__global__ __launch_bounds__(512, 4)
void vl_main(const float* __restrict__ x,
             const float* __restrict__ muw,
             const float* __restrict__ rhow,
             const float* __restrict__ epsw,
             const float* __restrict__ mub,
             const float* __restrict__ rhob,
             const float* __restrict__ epsb,
             float* __restrict__ out)
{
    // A tile [256][32] f16 + B tile [128][32] f16, double-buffered = 48 KiB
    // -> 2 blocks/CU (96 KiB LDS, 16 waves/CU): one block's loads cover the
    // other block's barrier drains.
    __shared__ __align__(16) f16 sm[2][BATCH * BK + BN * BK];

    const int t    = threadIdx.x;
    const int lane = t & 63;
    const int wid  = t >> 6;     // 0..7
    const int wm   = wid >> 1;   // 0..3 : m0 = wm*64
    const int wn   = wid & 1;    // 0..1 : n0 = wn*64

    // XCD-aware mapping: XCD (= bx%8) owns one k-split; its 1 MiB x-chunk
    // stays L2-resident across the XCD's 64 blocks.
    const int bx = blockIdx.x;
    const int sk = bx & 7;       // 0..7 k-split == XCD
    const int nb = bx >> 3;      // 0..63 n-block
    const int k_base = sk * KSPL;
    const int n_base = nb * BN;

    // staging assignment: thread -> (row = t>>2, 16B slot = t&3)
    const int slot = t & 3;
    const int row  = t >> 2;     // 0..127

    const float* xp0 = x + (size_t)row * IN_DIM + k_base + slot * 8;
    const float* xp1 = xp0 + (size_t)128 * IN_DIM;
    const size_t woff = (size_t)(n_base + row) * IN_DIM + k_base + slot * 8;
    const float* mup = muw  + woff;
    const float* rhp = rhow + woff;
    const float* epp = epsw + woff;

    // XOR-swizzled LDS half-indices; write side covers each row's full 64 B
    // with 4 lanes -> 2-way regardless of the permutation.
    const int a_sw  = (slot ^ ((row >> 1) & 3)) << 3;
    const int a_st0 = row * BK + a_sw;
    const int a_st1 = (row + 128) * BK + a_sw;   // (row+128)>>1 & 3 == (row>>1)&3
    const int b_st  = BATCH * BK + row * BK + a_sw;

    f32x4 acc[4][4];
#pragma unroll
    for (int i = 0; i < 4; ++i)
#pragma unroll
        for (int j = 0; j < 4; ++j)
            acc[i][j] = (f32x4){0.f, 0.f, 0.f, 0.f};

    // ONE named register set (static indexing -> no scratch, rule #20).
    f32x4 A0a, A0b, A1a, A1b, M0, M1, R0, R1, E0, E1;

    // Prologue: k0 -> buf0.
    ISSUE(0);
    COMMIT(0);
    BARRIER();

    // Depth-1 pipeline, unrolled x2 for static buffer indices:
    //   ISSUE(s+1) ; MSTEP(cur) ; COMMIT(next) ; BARRIER
    for (int s = 0; s < NSTEP; s += 2) {
        ISSUE(s + 1);
        MSTEP(0);
        COMMIT(1);
        BARRIER();
        if (s + 2 < NSTEP) ISSUE(s + 2);
        MSTEP(1);
        if (s + 2 < NSTEP) COMMIT(0);
        BARRIER();
    }

    // Epilogue: bias (only k-split 0 adds it), then one f32 atomicAdd per
    // output element per split (d_out zeroed by hipMemsetAsync in launch).
    float bias[4] = {0.f, 0.f, 0.f, 0.f};
    if (sk == 0) {
#pragma unroll
        for (int j = 0; j < 4; ++j) {
            const int c = n_base + wn * 64 + j * 16 + (lane & 15);
            bias[j] = mub[c] + softplus_f(rhob[c]) * epsb[c];
        }
    }
#pragma unroll
    for (int i = 0; i < 4; ++i) {
        const int r = wm * 64 + i * 16 + ((lane >> 4) << 2);
#pragma unroll
        for (int j = 0; j < 4; ++j) {
            const int c = n_base + wn * 64 + j * 16 + (lane & 15);
            float* po = out + (size_t)r * OUT_DIM + c;
#pragma unroll
            for (int q = 0; q < 4; ++q)
                atomicAdd(po + (size_t)q * OUT_DIM, acc[i][j][q] + bias[j]);
        }
    }
}

extern "C" void kernel_launch(void* const* d_in, const int* in_sizes, int n_in,
                              void* d_out, int out_size, void* d_ws, size_t ws_size,
                              hipStream_t stream) {
    (void)in_sizes; (void)n_in; (void)d_ws; (void)ws_size;
    const float* x    = (const float*)d_in[0];
    const float* muw  = (const float*)d_in[1];
    const float* rhow = (const float*)d_in[2];
    const float* mub  = (const float*)d_in[3];
    const float* rhob = (const float*)d_in[4];
    const float* epsw = (const float*)d_in[5];
    const float* epsb = (const float*)d_in[6];
    float* out = (float*)d_out;

    hipMemsetAsync(out, 0, (size_t)out_size * sizeof(float), stream);
    vl_main<<<dim3(512), dim3(512), 0, stream>>>(x, muw, rhow, epsw,
                                                 mub, rhob, epsb, out);
}

// Round 4
// 259.510 us; speedup vs baseline: 2.0274x; 1.0791x over previous
//
#include <hip/hip_runtime.h>

typedef _Float16 f16;
typedef _Float16 f16x8 __attribute__((ext_vector_type(8)));
typedef float f32x4 __attribute__((ext_vector_type(4)));

#define IN_DIM  8192
#define OUT_DIM 8192
#define BATCH   256
#define BK      32
#define BN      128
#define NSPLIT  4
#define KSPL    (IN_DIM / NSPLIT)   /* 2048 per split */
#define NSTEP   (KSPL / BK)         /* 64 K-steps */

__device__ __forceinline__ float softplus_f(float r) {
    // rho ~ N(-3, 0.1): exp can't overflow; fast hw exp/log is ~1e-5 rel,
    // far below the f16 rounding we apply afterwards.
    return __logf(1.0f + __expf(r));
}

// ---- W staging: one named register set = 6 x f32x4 = 24 VGPRs ----
#define ISSUE_W(S, Ma,Mb,Ra,Rb,Ea,Eb) do {                                   \
    const int o_ = (S) * BK;                                                 \
    Ma = *(const f32x4*)(mup + o_);   Mb = *(const f32x4*)(mup + o_ + 4);    \
    Ra = *(const f32x4*)(rhp + o_);   Rb = *(const f32x4*)(rhp + o_ + 4);    \
    Ea = *(const f32x4*)(epp + o_);   Eb = *(const f32x4*)(epp + o_ + 4);    \
} while (0)

// softplus-combine + cvt + one ds_write_b128 into LDS buffer BUF.
#define COMMIT_W(BUF, Ma,Mb,Ra,Rb,Ea,Eb) do {                                \
    f16x8 wv_;                                                               \
    _Pragma("unroll")                                                        \
    for (int q_ = 0; q_ < 4; ++q_) {                                         \
        wv_[q_]   = (f16)(Ma[q_] + softplus_f(Ra[q_]) * Ea[q_]);             \
        wv_[4+q_] = (f16)(Mb[q_] + softplus_f(Rb[q_]) * Eb[q_]);             \
    }                                                                        \
    *(f16x8*)&sm[BUF][b_st] = wv_;                                           \
} while (0)

// ---- A path: per-wave direct global loads (L2-resident x chunk), no LDS ----
// 8 x f32x4 = 32 VGPRs, depth-1 prefetch.
#define ISSUE_A(S) do {                                                      \
    const int o_ = (S) * BK;                                                 \
    Ap0 = *(const f32x4*)(xa0 + o_);  Ap1 = *(const f32x4*)(xa0 + o_ + 4);   \
    Ap2 = *(const f32x4*)(xa1 + o_);  Ap3 = *(const f32x4*)(xa1 + o_ + 4);   \
    Ap4 = *(const f32x4*)(xa2 + o_);  Ap5 = *(const f32x4*)(xa2 + o_ + 4);   \
    Ap6 = *(const f32x4*)(xa3 + o_);  Ap7 = *(const f32x4*)(xa3 + o_ + 4);   \
} while (0)

#define CVT_A() do {                                                         \
    _Pragma("unroll")                                                        \
    for (int q_ = 0; q_ < 4; ++q_) {                                         \
        af0[q_] = (f16)Ap0[q_];  af0[4+q_] = (f16)Ap1[q_];                   \
        af1[q_] = (f16)Ap2[q_];  af1[4+q_] = (f16)Ap3[q_];                   \
        af2[q_] = (f16)Ap4[q_];  af2[4+q_] = (f16)Ap5[q_];                   \
        af3[q_] = (f16)Ap6[q_];  af3[4+q_] = (f16)Ap7[q_];                   \
    }                                                                        \
} while (0)

// One K-step of MFMA. B fragments from W LDS with the verified 0-conflict
// swizzle (slot ^ ((row>>1)&3)); A fragments already in af0..af3.
#define MSTEP(BUF) do {                                                      \
    f16x8 bf_[4];                                                            \
    _Pragma("unroll")                                                        \
    for (int j_ = 0; j_ < 4; ++j_) {                                         \
        const int br_ = wn * 64 + j_ * 16 + (lane & 15);                     \
        bf_[j_] = *(const f16x8*)&sm[BUF][br_ * BK +                         \
                    (((lane >> 4) ^ ((br_ >> 1) & 3)) << 3)];                \
    }                                                                        \
    _Pragma("unroll")                                                        \
    for (int j_ = 0; j_ < 4; ++j_) {                                         \
        acc[0][j_] = __builtin_amdgcn_mfma_f32_16x16x32_f16(af0, bf_[j_], acc[0][j_], 0, 0, 0); \
        acc[1][j_] = __builtin_amdgcn_mfma_f32_16x16x32_f16(af1, bf_[j_], acc[1][j_], 0, 0, 0); \
        acc[2][j_] = __builtin_amdgcn_mfma_f32_16x16x32_f16(af2, bf_[j_], acc[2][j_], 0, 0, 0); \
        acc[3][j_] = __builtin_amdgcn_mfma_f32_16x16x32_f16(af3, bf_[j_], acc[3][j_], 0, 0, 0); \
    }                                                                        \
} while (0)

// Barrier draining only LDS ops; global loads stay in flight across it
// (vmcnt waits are compiler-counted at each use point).
#define BARRIER() do {                                                       \
    asm volatile("s_waitcnt lgkmcnt(0)" ::: "memory");                       \
    __builtin_amdgcn_s_barrier();                                            \
} while (0)

__global__ __launch_bounds__(512, 2)
void vl_main(const float* __restrict__ x,
             const float* __restrict__ muw,
             const float* __restrict__ rhow,
             const float* __restrict__ epsw,
             const float* __restrict__ mub,
             const float* __restrict__ rhob,
             const float* __restrict__ epsb,
             float* __restrict__ out)
{
    // W tile only: [128][32] f16, double-buffered = 16 KiB.
    __shared__ __align__(16) f16 sm[2][BN * BK];

    const int t    = threadIdx.x;
    const int lane = t & 63;
    const int wid  = t >> 6;     // 0..7
    const int wm   = wid >> 1;   // 0..3 : m0 = wm*64
    const int wn   = wid & 1;    // 0..1 : n0 = wn*64

    // XCD-aware mapping (R1 form): XCD pair owns one k-split; its 2 MiB
    // f32 x-chunk stays L2-resident (per-step slice is only 32 KiB hot).
    const int bx = blockIdx.x;
    const int x7 = bx & 7;
    const int sk = x7 >> 1;                      // 0..3 k-split
    const int nb = (x7 & 1) * 32 + (bx >> 3);    // 0..63 n-block
    const int k_base = sk * KSPL;
    const int n_base = nb * BN;

    // W staging: thread -> (row = t>>2, 16B slot = t&3)
    const int slot = t & 3;
    const int row  = t >> 2;     // 0..127
    const size_t woff = (size_t)(n_base + row) * IN_DIM + k_base + slot * 8;
    const float* mup = muw  + woff;
    const float* rhp = rhow + woff;
    const float* epp = epsw + woff;

    // XOR-swizzled W LDS index (write side; read uses same involution).
    const int b_st = row * BK + ((slot ^ ((row >> 1) & 3)) << 3);

    // A-fragment global pointers: lane (l&15) = row-in-16, (l>>4) = k-octet.
    const int kf = (lane >> 4) * 8;
    const float* xa0 = x + (size_t)(wm * 64 +  0 + (lane & 15)) * IN_DIM + k_base + kf;
    const float* xa1 = x + (size_t)(wm * 64 + 16 + (lane & 15)) * IN_DIM + k_base + kf;
    const float* xa2 = x + (size_t)(wm * 64 + 32 + (lane & 15)) * IN_DIM + k_base + kf;
    const float* xa3 = x + (size_t)(wm * 64 + 48 + (lane & 15)) * IN_DIM + k_base + kf;

    f32x4 acc[4][4];
#pragma unroll
    for (int i = 0; i < 4; ++i)
#pragma unroll
        for (int j = 0; j < 4; ++j)
            acc[i][j] = (f32x4){0.f, 0.f, 0.f, 0.f};

    // Named register sets (static indexing -> no scratch, rule #20).
    f32x4 Ap0, Ap1, Ap2, Ap3, Ap4, Ap5, Ap6, Ap7;        // A depth-1 (32 regs)
    f32x4 M0a, M0b, R0a, R0b, E0a, E0b;                  // W set0 (24 regs)
    f32x4 M1a, M1b, R1a, R1b, E1a, E1b;                  // W set1 (24 regs)
    f16x8 af0, af1, af2, af3;                            // converted A frags

    // Prologue: A(0); W(0)->set0; W(1)->set1; commit W(0)->buf0.
    ISSUE_A(0);
    ISSUE_W(0, M0a, M0b, R0a, R0b, E0a, E0b);
    ISSUE_W(1, M1a, M1b, R1a, R1b, E1a, E1b);
    COMMIT_W(0, M0a, M0b, R0a, R0b, E0a, E0b);
    BARRIER();

    for (int s = 0; s < NSTEP; s += 2) {
        // ---- even phase: K = s, compute buf0 ----
        CVT_A();                                          // waits A(s), vmcnt-counted
        ISSUE_A(s + 1);                                   // A(s+1) (s+1 < NSTEP always)
        if (s + 2 < NSTEP) ISSUE_W(s + 2, M0a, M0b, R0a, R0b, E0a, E0b);
        MSTEP(0);
        COMMIT_W(1, M1a, M1b, R1a, R1b, E1a, E1b);        // waits W(s+1), keeps A+W(s+2) in flight
        BARRIER();
        // ---- odd phase: K = s+1, compute buf1 ----
        CVT_A();                                          // waits A(s+1)
        if (s + 2 < NSTEP) ISSUE_A(s + 2);
        if (s + 3 < NSTEP) ISSUE_W(s + 3, M1a, M1b, R1a, R1b, E1a, E1b);
        MSTEP(1);
        if (s + 2 < NSTEP) {
            COMMIT_W(0, M0a, M0b, R0a, R0b, E0a, E0b);    // waits W(s+2)
            BARRIER();
        }
    }

    // Epilogue: bias (only k-split 0 adds it), then one f32 atomicAdd per
    // output element per split (d_out zeroed by hipMemsetAsync in launch).
    float bias[4] = {0.f, 0.f, 0.f, 0.f};
    if (sk == 0) {
#pragma unroll
        for (int j = 0; j < 4; ++j) {
            const int c = n_base + wn * 64 + j * 16 + (lane & 15);
            bias[j] = mub[c] + softplus_f(rhob[c]) * epsb[c];
        }
    }
#pragma unroll
    for (int i = 0; i < 4; ++i) {
        const int r = wm * 64 + i * 16 + ((lane >> 4) << 2);
#pragma unroll
        for (int j = 0; j < 4; ++j) {
            const int c = n_base + wn * 64 + j * 16 + (lane & 15);
            float* po = out + (size_t)r * OUT_DIM + c;
#pragma unroll
            for (int q = 0; q < 4; ++q)
                atomicAdd(po + (size_t)q * OUT_DIM, acc[i][j][q] + bias[j]);
        }
    }
}

extern "C" void kernel_launch(void* const* d_in, const int* in_sizes, int n_in,
                              void* d_out, int out_size, void* d_ws, size_t ws_size,
                              hipStream_t stream) {
    (void)in_sizes; (void)n_in; (void)d_ws; (void)ws_size;
    const float* x    = (const float*)d_in[0];
    const float* muw  = (const float*)d_in[1];
    const float* rhow = (const float*)d_in[2];
    const float* mub  = (const float*)d_in[3];
    const float* rhob = (const float*)d_in[4];
    const float* epsw = (const float*)d_in[5];
    const float* epsb = (const float*)d_in[6];
    float* out = (float*)d_out;

    hipMemsetAsync(out, 0, (size_t)out_size * sizeof(float), stream);
    vl_main<<<dim3(256), dim3(512), 0, stream>>>(x, muw, rhow, epsw,
                                                 mub, rhob, epsb, out);
}

// Round 5
// 245.561 us; speedup vs baseline: 2.1425x; 1.0568x over previous
//
#include <hip/hip_runtime.h>

typedef _Float16 f16;
typedef _Float16 f16x8 __attribute__((ext_vector_type(8)));
typedef float f32x4 __attribute__((ext_vector_type(4)));

#define IN_DIM  8192
#define OUT_DIM 8192
#define NSPLIT  4
#define KSPL    (IN_DIM / NSPLIT)   /* 2048 per split */
#define BKM     64                  /* macro K-step (256 B per W row visit) */
#define NM      (KSPL / BKM)        /* 32 macro steps */

__device__ __forceinline__ float softplus_f(float r) {
    return __logf(1.0f + __expf(r));
}

// Inline-asm 16B global load: volatile -> compiler cannot sink it to the use.
// No compiler waitcnt is generated for these; we count vmcnt by hand.
#define GLD16(dst, p, LIT) \
    asm volatile("global_load_dwordx4 %0, %1, off offset:" LIT \
                 : "=&v"(dst) : "v"(p))

#define SCHED0() __builtin_amdgcn_sched_barrier(0)

// Issue one W macro-tile (12 loads, FIFO-counted) into a named set.
#define ISSUE_W(M0,M1,M2,M3,R0,R1,R2,R3,E0,E1,E2,E3, S) do {                 \
    const float* pm_ = mup + (size_t)(S) * BKM;                              \
    const float* pr_ = rhp + (size_t)(S) * BKM;                              \
    const float* pe_ = epp + (size_t)(S) * BKM;                              \
    GLD16(M0, pm_, "0");  GLD16(M1, pm_, "16");                              \
    GLD16(M2, pm_, "32"); GLD16(M3, pm_, "48");                              \
    GLD16(R0, pr_, "0");  GLD16(R1, pr_, "16");                              \
    GLD16(R2, pr_, "32"); GLD16(R3, pr_, "48");                              \
    GLD16(E0, pe_, "0");  GLD16(E1, pe_, "16");                              \
    GLD16(E2, pe_, "32"); GLD16(E3, pe_, "48");                              \
} while (0)

// Issue one A macro-tile (8 loads) into the single A set.
#define ISSUE_A(S) do {                                                      \
    const float* pa_ = xap + (size_t)(S) * BKM;                              \
    GLD16(Aa, pa_, "0");   GLD16(Ab, pa_, "16");                             \
    GLD16(Ac, pa_, "32");  GLD16(Ad, pa_, "48");                             \
    GLD16(Ae, pa_, "64");  GLD16(Af, pa_, "80");                             \
    GLD16(Ag, pa_, "96");  GLD16(Ah, pa_, "112");                            \
} while (0)

// softplus-combine 16 f32 -> 2 f16x8 ds_writes into W buffer BUF.
#define COMMIT_W(BUF, M0,M1,M2,M3,R0,R1,R2,R3,E0,E1,E2,E3) do {              \
    f16x8 w0_, w1_;                                                          \
    _Pragma("unroll")                                                        \
    for (int q_ = 0; q_ < 4; ++q_) {                                         \
        w0_[q_]   = (f16)(M0[q_] + softplus_f(R0[q_]) * E0[q_]);             \
        w0_[4+q_] = (f16)(M1[q_] + softplus_f(R1[q_]) * E1[q_]);             \
        w1_[q_]   = (f16)(M2[q_] + softplus_f(R2[q_]) * E2[q_]);             \
        w1_[4+q_] = (f16)(M3[q_] + softplus_f(R3[q_]) * E3[q_]);             \
    }                                                                        \
    *(f16x8*)&smW[BUF][ws0] = w0_;                                           \
    *(f16x8*)&smW[BUF][ws1] = w1_;                                           \
} while (0)

// cvt 32 f32 -> 4 f16x8 ds_writes into the single A buffer.
#define COMMIT_A() do {                                                      \
    f16x8 a0_, a1_, a2_, a3_;                                                \
    _Pragma("unroll")                                                        \
    for (int q_ = 0; q_ < 4; ++q_) {                                         \
        a0_[q_] = (f16)Aa[q_];  a0_[4+q_] = (f16)Ab[q_];                     \
        a1_[q_] = (f16)Ac[q_];  a1_[4+q_] = (f16)Ad[q_];                     \
        a2_[q_] = (f16)Ae[q_];  a2_[4+q_] = (f16)Af[q_];                     \
        a3_[q_] = (f16)Ag[q_];  a3_[4+q_] = (f16)Ah[q_];                     \
    }                                                                        \
    *(f16x8*)&smA[as0] = a0_;  *(f16x8*)&smA[as1] = a1_;                     \
    *(f16x8*)&smA[as2] = a2_;  *(f16x8*)&smA[as3] = a3_;                     \
} while (0)

// Half-macro-step of MFMA (k=32). Shared xor swizzle: row&7 == (lane&15)&7
// for all fragment rows (row offsets are multiples of 16).
#define MSTEP(B, HH) do {                                                    \
    const int ko_ = (HH) * 4 + (lane >> 4);                                  \
    const int rr_ = lane & 15;                                               \
    const int xw_ = (ko_ ^ (rr_ & 7)) << 3;                                  \
    f16x8 bf_[4];                                                            \
    _Pragma("unroll")                                                        \
    for (int j_ = 0; j_ < 4; ++j_)                                           \
        bf_[j_] = *(const f16x8*)&smW[B][(wn*64 + j_*16 + rr_)*BKM + xw_];   \
    _Pragma("unroll")                                                        \
    for (int i_ = 0; i_ < 4; ++i_) {                                         \
        const f16x8 af_ = *(const f16x8*)&smA[(wm*64 + i_*16 + rr_)*BKM + xw_]; \
        _Pragma("unroll")                                                    \
        for (int j_ = 0; j_ < 4; ++j_)                                       \
            acc[i_][j_] = __builtin_amdgcn_mfma_f32_16x16x32_f16(            \
                af_, bf_[j_], acc[i_][j_], 0, 0, 0);                         \
    }                                                                        \
} while (0)

// Barrier draining only LDS ops; asm global loads stay in flight across it.
#define BARRIER() do {                                                       \
    asm volatile("s_waitcnt lgkmcnt(0)" ::: "memory");                       \
    __builtin_amdgcn_s_barrier();                                            \
} while (0)

__global__ __launch_bounds__(512, 2)
void vl_main(const float* __restrict__ x,
             const float* __restrict__ muw,
             const float* __restrict__ rhow,
             const float* __restrict__ epsw,
             const float* __restrict__ mub,
             const float* __restrict__ rhob,
             const float* __restrict__ epsb,
             float* __restrict__ out)
{
    // A: single-buffered [256][64] f16 = 32 KiB; W: double-buffered
    // [2][128][64] f16 = 32 KiB. Total 64 KiB static.
    __shared__ __align__(16) f16 smA[256 * BKM];
    __shared__ __align__(16) f16 smW[2][128 * BKM];

    const int t    = threadIdx.x;
    const int lane = t & 63;
    const int wid  = t >> 6;     // 0..7
    const int wm   = wid >> 1;   // 0..3 : m0 = wm*64
    const int wn   = wid & 1;    // 0..1 : n0 = wn*64

    // XCD-aware mapping (R1 form): an XCD pair owns one k-split; its 2 MiB
    // f32 x-chunk stays L2-resident.
    const int bx = blockIdx.x;
    const int x7 = bx & 7;
    const int sk = x7 >> 1;                      // 0..3 k-split
    const int nb = (x7 & 1) * 32 + (bx >> 3);    // 0..63 n-block
    const int k_base = sk * KSPL;
    const int n_base = nb * 128;

    // ---- W staging map: thread -> (row = t>>2, 64B slot = t&3) ----
    const int slot = t & 3;
    const int rw   = t >> 2;     // 0..127
    const size_t woff = (size_t)(n_base + rw) * IN_DIM + k_base + slot * 16;
    const float* mup = muw  + woff;
    const float* rhp = rhow + woff;
    const float* epp = epsw + woff;
    const int ws0 = rw * BKM + (((2*slot + 0) ^ (rw & 7)) << 3);
    const int ws1 = rw * BKM + (((2*slot + 1) ^ (rw & 7)) << 3);

    // ---- A staging map: thread -> (row = t>>1, half h = t&1) ----
    const int ra = t >> 1;       // 0..255
    const int ha = t & 1;
    const float* xap = x + (size_t)ra * IN_DIM + k_base + ha * 32;
    const int as0 = ra * BKM + (((ha*4 + 0) ^ (ra & 7)) << 3);
    const int as1 = ra * BKM + (((ha*4 + 1) ^ (ra & 7)) << 3);
    const int as2 = ra * BKM + (((ha*4 + 2) ^ (ra & 7)) << 3);
    const int as3 = ra * BKM + (((ha*4 + 3) ^ (ra & 7)) << 3);

    f32x4 acc[4][4];
#pragma unroll
    for (int i = 0; i < 4; ++i)
#pragma unroll
        for (int j = 0; j < 4; ++j)
            acc[i][j] = (f32x4){0.f, 0.f, 0.f, 0.f};

    // Named asm-load register sets (static, rule #20).
    f32x4 Aa, Ab, Ac, Ad, Ae, Af, Ag, Ah;                         // A: 32 regs
    f32x4 M00,M01,M02,M03, R00,R01,R02,R03, E00,E01,E02,E03;      // W set0: 48
    f32x4 M10,M11,M12,M13, R10,R11,R12,R13, E10,E11,E12,E13;      // W set1: 48

    // Prologue: W(0)->set0, A(0); drain; commit both; W(1)->set0.
    ISSUE_W(M00,M01,M02,M03,R00,R01,R02,R03,E00,E01,E02,E03, 0);
    ISSUE_A(0);
    asm volatile("s_waitcnt vmcnt(0)"); SCHED0();
    COMMIT_W(0, M00,M01,M02,M03,R00,R01,R02,R03,E00,E01,E02,E03);
    COMMIT_A();
    ISSUE_W(M00,M01,M02,M03,R00,R01,R02,R03,E00,E01,E02,E03, 1);
    BARRIER();
    // loop-top invariant: 12 loads in flight (W(s+1)).

    for (int s = 0; s < NM; s += 2) {
        // ---- EVEN: compute {A(s), W(s) in smW[0]}; W(s+1) is in set0 ----
        ISSUE_A(s + 1 < NM ? s + 1 : NM - 1);                 // flight: 20
        ISSUE_W(M10,M11,M12,M13,R10,R11,R12,R13,E10,E11,E12,E13,
                s + 2 < NM ? s + 2 : NM - 1);                 // flight: 32
        MSTEP(0, 0); MSTEP(0, 1);
        asm volatile("s_waitcnt vmcnt(20)"); SCHED0();        // W(s+1) landed
        COMMIT_W(1, M00,M01,M02,M03,R00,R01,R02,R03,E00,E01,E02,E03);
        BARRIER();                                            // A reads done
        asm volatile("s_waitcnt vmcnt(12)"); SCHED0();        // A(s+1) landed
        COMMIT_A();
        BARRIER();                                            // flight: 12

        // ---- ODD: compute {A(s+1), W(s+1) in smW[1]}; W(s+2) in set1 ----
        ISSUE_A(s + 2 < NM ? s + 2 : NM - 1);
        ISSUE_W(M00,M01,M02,M03,R00,R01,R02,R03,E00,E01,E02,E03,
                s + 3 < NM ? s + 3 : NM - 1);
        MSTEP(1, 0); MSTEP(1, 1);
        asm volatile("s_waitcnt vmcnt(20)"); SCHED0();
        COMMIT_W(0, M10,M11,M12,M13,R10,R11,R12,R13,E10,E11,E12,E13);
        BARRIER();
        asm volatile("s_waitcnt vmcnt(12)"); SCHED0();
        COMMIT_A();
        BARRIER();
    }
    asm volatile("s_waitcnt vmcnt(0)" ::: "memory"); SCHED0();

    // Epilogue: bias (k-split 0 only), one f32 atomicAdd per element per split.
    float bias[4] = {0.f, 0.f, 0.f, 0.f};
    if (sk == 0) {
#pragma unroll
        for (int j = 0; j < 4; ++j) {
            const int c = n_base + wn * 64 + j * 16 + (lane & 15);
            bias[j] = mub[c] + softplus_f(rhob[c]) * epsb[c];
        }
    }
#pragma unroll
    for (int i = 0; i < 4; ++i) {
        const int r = wm * 64 + i * 16 + ((lane >> 4) << 2);
#pragma unroll
        for (int j = 0; j < 4; ++j) {
            const int c = n_base + wn * 64 + j * 16 + (lane & 15);
            float* po = out + (size_t)r * OUT_DIM + c;
#pragma unroll
            for (int q = 0; q < 4; ++q)
                atomicAdd(po + (size_t)q * OUT_DIM, acc[i][j][q] + bias[j]);
        }
    }
}

extern "C" void kernel_launch(void* const* d_in, const int* in_sizes, int n_in,
                              void* d_out, int out_size, void* d_ws, size_t ws_size,
                              hipStream_t stream) {
    (void)in_sizes; (void)n_in; (void)d_ws; (void)ws_size;
    const float* x    = (const float*)d_in[0];
    const float* muw  = (const float*)d_in[1];
    const float* rhow = (const float*)d_in[2];
    const float* mub  = (const float*)d_in[3];
    const float* rhob = (const float*)d_in[4];
    const float* epsw = (const float*)d_in[5];
    const float* epsb = (const float*)d_in[6];
    float* out = (float*)d_out;

    hipMemsetAsync(out, 0, (size_t)out_size * sizeof(float), stream);
    vl_main<<<dim3(256), dim3(512), 0, stream>>>(x, muw, rhow, epsw,
                                                 mub, rhob, epsb, out);
}

// Round 6
// 217.234 us; speedup vs baseline: 2.4219x; 1.1304x over previous
//
#include <hip/hip_runtime.h>

typedef _Float16 f16;
typedef _Float16 f16x8 __attribute__((ext_vector_type(8)));
typedef float f32x4 __attribute__((ext_vector_type(4)));

#define IN_DIM  8192
#define OUT_DIM 8192
#define BK      32
#define BN      64
#define NSPLIT  4
#define KSPL    (IN_DIM / NSPLIT)   /* 2048 per split */
#define NSTEP   (KSPL / BK)         /* 64 K-steps */

__device__ __forceinline__ float softplus_f(float r) {
    // rho ~ N(-3, 0.1): exp can't overflow; fast hw exp/log is ~1e-5 rel,
    // far below the f16 rounding applied afterwards.
    return __logf(1.0f + __expf(r));
}

// One K-step's loads into a named register set (14 x f32x4 = 56 VGPRs).
// A: 4 row-groups (rows rgrp+64g) x 8 f32; W: mu/rho/eps x 8 f32.
#define ISSUE(S, Aa0,Aa1,Ab0,Ab1,Ac0,Ac1,Ad0,Ad1, M0,M1,R0,R1,E0,E1) do {   \
    const int o_ = (S) * BK;                                                 \
    Aa0 = *(const f32x4*)(xa + o_);                                          \
    Aa1 = *(const f32x4*)(xa + o_ + 4);                                      \
    Ab0 = *(const f32x4*)(xa + (size_t)64 * IN_DIM + o_);                    \
    Ab1 = *(const f32x4*)(xa + (size_t)64 * IN_DIM + o_ + 4);                \
    Ac0 = *(const f32x4*)(xa + (size_t)128 * IN_DIM + o_);                   \
    Ac1 = *(const f32x4*)(xa + (size_t)128 * IN_DIM + o_ + 4);               \
    Ad0 = *(const f32x4*)(xa + (size_t)192 * IN_DIM + o_);                   \
    Ad1 = *(const f32x4*)(xa + (size_t)192 * IN_DIM + o_ + 4);               \
    M0  = *(const f32x4*)(mup + o_);   M1 = *(const f32x4*)(mup + o_ + 4);   \
    R0  = *(const f32x4*)(rhp + o_);   R1 = *(const f32x4*)(rhp + o_ + 4);   \
    E0  = *(const f32x4*)(epp + o_);   E1 = *(const f32x4*)(epp + o_ + 4);   \
} while (0)

// cvt A + softplus-combine W, ds_write_b128 into buffer BUF.
// Swizzle is row-invariant across the 4 A row-groups ((r+64g)>>1 & 3 ==
// (r>>1)&3), so one precomputed swizzled base + g*64*BK strides.
#define COMMIT(BUF, Aa0,Aa1,Ab0,Ab1,Ac0,Ac1,Ad0,Ad1, M0,M1,R0,R1,E0,E1) do { \
    f16x8 a0_, a1_, a2_, a3_, wv_;                                           \
    _Pragma("unroll")                                                        \
    for (int q_ = 0; q_ < 4; ++q_) {                                         \
        a0_[q_] = (f16)Aa0[q_];  a0_[4+q_] = (f16)Aa1[q_];                   \
        a1_[q_] = (f16)Ab0[q_];  a1_[4+q_] = (f16)Ab1[q_];                   \
        a2_[q_] = (f16)Ac0[q_];  a2_[4+q_] = (f16)Ac1[q_];                   \
        a3_[q_] = (f16)Ad0[q_];  a3_[4+q_] = (f16)Ad1[q_];                   \
        wv_[q_]   = (f16)(M0[q_] + softplus_f(R0[q_]) * E0[q_]);             \
        wv_[4+q_] = (f16)(M1[q_] + softplus_f(R1[q_]) * E1[q_]);             \
    }                                                                        \
    *(f16x8*)&smA[BUF][ast + 0 * 64 * BK] = a0_;                             \
    *(f16x8*)&smA[BUF][ast + 1 * 64 * BK] = a1_;                             \
    *(f16x8*)&smA[BUF][ast + 2 * 64 * BK] = a2_;                             \
    *(f16x8*)&smA[BUF][ast + 3 * 64 * BK] = a3_;                             \
    *(f16x8*)&smW[BUF][wst] = wv_;                                           \
} while (0)

// One K-step of MFMA: per wave 4x4 fragments of 16x16x32 f16 (64x64 tile;
// all 4 waves share the same B fragments -> LDS broadcast, no conflict).
// Swizzle (ko ^ ((row>>1)&3)) measured 0-conflict in R2/R3.
#define MSTEP(B) do {                                                        \
    const int rr_ = lane & 15;                                               \
    const int ko_ = lane >> 4;                                               \
    f16x8 bf_[4];                                                            \
    _Pragma("unroll")                                                        \
    for (int j_ = 0; j_ < 4; ++j_) {                                         \
        const int br_ = j_ * 16 + rr_;                                       \
        bf_[j_] = *(const f16x8*)&smW[B][br_ * BK + ((ko_ ^ ((br_ >> 1) & 3)) << 3)]; \
    }                                                                        \
    _Pragma("unroll")                                                        \
    for (int i_ = 0; i_ < 4; ++i_) {                                         \
        const int ar_ = wv * 64 + i_ * 16 + rr_;                             \
        const f16x8 af_ = *(const f16x8*)&smA[B][ar_ * BK + ((ko_ ^ ((ar_ >> 1) & 3)) << 3)]; \
        _Pragma("unroll")                                                    \
        for (int j_ = 0; j_ < 4; ++j_)                                       \
            acc[i_][j_] = __builtin_amdgcn_mfma_f32_16x16x32_f16(            \
                af_, bf_[j_], acc[i_][j_], 0, 0, 0);                         \
    }                                                                        \
} while (0)

// Barrier draining only LDS ops; global loads stay in flight across it.
#define BARRIER() do {                                                       \
    asm volatile("s_waitcnt lgkmcnt(0)" ::: "memory");                       \
    __builtin_amdgcn_s_barrier();                                            \
} while (0)

__global__ __launch_bounds__(256, 2)
void vl_main(const float* __restrict__ x,
             const float* __restrict__ muw,
             const float* __restrict__ rhow,
             const float* __restrict__ epsw,
             const float* __restrict__ mub,
             const float* __restrict__ rhob,
             const float* __restrict__ epsb,
             float* __restrict__ out)
{
    // A [2][256][32] f16 = 32 KiB + W [2][64][32] f16 = 8 KiB -> 40 KiB:
    // TWO blocks co-resident per CU = two independent barrier domains, so
    // one block's waves issue VMEM while the other drains at its barrier.
    __shared__ __align__(16) f16 smA[2][256 * BK];
    __shared__ __align__(16) f16 smW[2][BN * BK];

    const int t    = threadIdx.x;
    const int lane = t & 63;
    const int wv   = t >> 6;     // 0..3 : wave owns rows [wv*64, wv*64+64)

    // XCD-aware mapping: an XCD pair owns one k-split (2 MiB f32 x-chunk
    // L2-resident); each XCD covers 64 consecutive n-blocks.
    const int bx  = blockIdx.x;
    const int xcd = bx & 7;
    const int idx = bx >> 3;                 // 0..63
    const int sk  = xcd >> 1;                // 0..3 k-split
    const int nb  = (xcd & 1) * 64 + idx;    // 0..127 n-block
    const int k_base = sk * KSPL;
    const int n_base = nb * BN;

    // Staging map: thread -> (row-group rgrp = t>>2, 32B slot = t&3).
    const int slot = t & 3;
    const int rgrp = t >> 2;     // 0..63

    const float* xa = x + (size_t)rgrp * IN_DIM + k_base + slot * 8;
    const size_t woff = (size_t)(n_base + rgrp) * IN_DIM + k_base + slot * 8;
    const float* mup = muw  + woff;
    const float* rhp = rhow + woff;
    const float* epp = epsw + woff;

    // XOR-swizzled LDS write indices (same involution as the read side).
    const int sw_ = (slot ^ ((rgrp >> 1) & 3)) << 3;
    const int ast = rgrp * BK + sw_;
    const int wst = rgrp * BK + sw_;

    f32x4 acc[4][4];
#pragma unroll
    for (int i = 0; i < 4; ++i)
#pragma unroll
        for (int j = 0; j < 4; ++j)
            acc[i][j] = (f32x4){0.f, 0.f, 0.f, 0.f};

    // Two named register sets (static indexing -> no scratch, rule #20).
    f32x4 Aa00,Aa10,Ab00,Ab10,Ac00,Ac10,Ad00,Ad10, M00,M10,R00,R10,E00,E10;  // set0
    f32x4 Aa01,Aa11,Ab01,Ab11,Ac01,Ac11,Ad01,Ad11, M01,M11,R01,R11,E01,E11;  // set1

    // Prologue: set0 <- k0, set1 <- k1, commit k0 into buf0.
    ISSUE(0, Aa00,Aa10,Ab00,Ab10,Ac00,Ac10,Ad00,Ad10, M00,M10,R00,R10,E00,E10);
    ISSUE(1, Aa01,Aa11,Ab01,Ab11,Ac01,Ac11,Ad01,Ad11, M01,M11,R01,R11,E01,E11);
    COMMIT(0, Aa00,Aa10,Ab00,Ab10,Ac00,Ac10,Ad00,Ad10, M00,M10,R00,R10,E00,E10);
    BARRIER();

    for (int s = 0; s < NSTEP; s += 2) {
        // even: compute buf0 (k=s), commit set1 (k=s+1) -> buf1, prefetch k+2.
        if (s + 2 < NSTEP)
            ISSUE(s + 2, Aa00,Aa10,Ab00,Ab10,Ac00,Ac10,Ad00,Ad10, M00,M10,R00,R10,E00,E10);
        MSTEP(0);
        COMMIT(1, Aa01,Aa11,Ab01,Ab11,Ac01,Ac11,Ad01,Ad11, M01,M11,R01,R11,E01,E11);
        BARRIER();
        // odd: compute buf1 (k=s+1), commit set0 (k=s+2) -> buf0, prefetch k+3.
        if (s + 3 < NSTEP)
            ISSUE(s + 3, Aa01,Aa11,Ab01,Ab11,Ac01,Ac11,Ad01,Ad11, M01,M11,R01,R11,E01,E11);
        MSTEP(1);
        if (s + 2 < NSTEP)
            COMMIT(0, Aa00,Aa10,Ab00,Ab10,Ac00,Ac10,Ad00,Ad10, M00,M10,R00,R10,E00,E10);
        BARRIER();
    }

    // Epilogue: bias (k-split 0 only), one f32 atomicAdd per output element
    // per split (d_out zeroed by hipMemsetAsync in launch).
    float bias[4] = {0.f, 0.f, 0.f, 0.f};
    if (sk == 0) {
#pragma unroll
        for (int j = 0; j < 4; ++j) {
            const int c = n_base + j * 16 + (lane & 15);
            bias[j] = mub[c] + softplus_f(rhob[c]) * epsb[c];
        }
    }
#pragma unroll
    for (int i = 0; i < 4; ++i) {
        const int r = wv * 64 + i * 16 + ((lane >> 4) << 2);
#pragma unroll
        for (int j = 0; j < 4; ++j) {
            const int c = n_base + j * 16 + (lane & 15);
            float* po = out + (size_t)r * OUT_DIM + c;
#pragma unroll
            for (int q = 0; q < 4; ++q)
                atomicAdd(po + (size_t)q * OUT_DIM, acc[i][j][q] + bias[j]);
        }
    }
}

extern "C" void kernel_launch(void* const* d_in, const int* in_sizes, int n_in,
                              void* d_out, int out_size, void* d_ws, size_t ws_size,
                              hipStream_t stream) {
    (void)in_sizes; (void)n_in; (void)d_ws; (void)ws_size;
    const float* x    = (const float*)d_in[0];
    const float* muw  = (const float*)d_in[1];
    const float* rhow = (const float*)d_in[2];
    const float* mub  = (const float*)d_in[3];
    const float* rhob = (const float*)d_in[4];
    const float* epsw = (const float*)d_in[5];
    const float* epsb = (const float*)d_in[6];
    float* out = (float*)d_out;

    hipMemsetAsync(out, 0, (size_t)out_size * sizeof(float), stream);
    vl_main<<<dim3(512), dim3(256), 0, stream>>>(x, muw, rhow, epsw,
                                                 mub, rhob, epsb, out);
}